// Round 1
// baseline (417.510 us; speedup 1.0000x reference)
//
#include <hip/hip_runtime.h>
#include <hip/hip_bf16.h>
#include <cstdint>
#include <cstddef>

typedef __bf16 bf16;
typedef __bf16 bf16x4 __attribute__((ext_vector_type(4)));
typedef __bf16 bf16x8 __attribute__((ext_vector_type(8)));
typedef float f32x4 __attribute__((ext_vector_type(4)));

#define MFMA16(a, b, c) __builtin_amdgcn_mfma_f32_16x16x32_bf16((a), (b), (c), 0, 0, 0)

// Problem constants
constexpr int Bsz = 4, SX = 2048, SC = 2048, Dm = 512, H = 8, DK = 64;

// ---------------------------------------------------------------------------
// Kernel 1: convert the 4 weight matrices (each 512x512 fp32) to bf16,
// packed contiguously: Wq | Wk | Wv | Wo
// ---------------------------------------------------------------------------
__global__ __launch_bounds__(256) void cvt_weights(
    const float* __restrict__ Wq, const float* __restrict__ Wk,
    const float* __restrict__ Wv, const float* __restrict__ Wo,
    bf16* __restrict__ out)
{
    int i = (blockIdx.x * 256 + threadIdx.x) * 4;   // 0 .. 4*262144-1
    int w = i >> 18;                                 // which weight
    int off = i & 262143;
    const float* src = (w == 0) ? Wq : (w == 1) ? Wk : (w == 2) ? Wv : Wo;
    float4 v = *(const float4*)(src + off);
    bf16x4 o = { (bf16)v.x, (bf16)v.y, (bf16)v.z, (bf16)v.w };
    *(bf16x4*)(out + i) = o;
}

// ---------------------------------------------------------------------------
// Kernel 2: Y = X @ W^T + bias.  X fp32 (M x 512), W bf16 (N-slice x 512).
// Block tile 128(M) x 64(N), BK=64, 256 threads = 4 waves (2x2 of 64x32).
// MODE 0: Y bf16 at [(b*8+h)*2048 + s]*64 + dk      (Q, K layout)
// MODE 1: Y bf16 at [(b*8+h)*64 + dk]*2048 + s      (V transposed)
// MODE 2: Y fp32 at m*512 + n                        (final output)
// ---------------------------------------------------------------------------
constexpr int LDSS = 72;  // padded k-stride (bf16 elems): +16B keeps alignment, breaks conflicts

template <int MODE>
__global__ __launch_bounds__(256) void proj_gemm(
    const float* __restrict__ X, const bf16* __restrict__ W,
    const float* __restrict__ bias, void* __restrict__ Yv)
{
    __shared__ alignas(16) bf16 As[128 * LDSS];
    __shared__ alignas(16) bf16 Bs[64 * LDSS];

    const int t = threadIdx.x;
    const int m0 = blockIdx.x * 128;
    const int n0 = blockIdx.y * 64;
    const int wid = t >> 6, lane = t & 63, lr = lane & 15, lq = lane >> 4;
    const int wm = (wid >> 1) * 64, wn = (wid & 1) * 32;

    f32x4 acc[4][2];
#pragma unroll
    for (int i = 0; i < 4; i++)
#pragma unroll
        for (int j = 0; j < 2; j++) acc[i][j] = f32x4{0.f, 0.f, 0.f, 0.f};

    for (int k0 = 0; k0 < Dm; k0 += 64) {
        // ---- stage A (fp32 -> bf16): 128 rows x 64 k, 2 threads/row ----
        {
            int row = t >> 1, half = t & 1;
            const float* src = X + (size_t)(m0 + row) * Dm + k0 + half * 32;
            bf16* dst = &As[row * LDSS + half * 32];
#pragma unroll
            for (int i = 0; i < 4; i++) {
                float4 v0 = *(const float4*)(src + i * 8);
                float4 v1 = *(const float4*)(src + i * 8 + 4);
                bf16x8 o = { (bf16)v0.x, (bf16)v0.y, (bf16)v0.z, (bf16)v0.w,
                             (bf16)v1.x, (bf16)v1.y, (bf16)v1.z, (bf16)v1.w };
                *(bf16x8*)(dst + i * 8) = o;
            }
        }
        // ---- stage B (bf16): 64 rows x 64 k, 4 threads/row ----
        {
            int row = t >> 2, q = t & 3;
            const bf16* src = W + (size_t)(n0 + row) * Dm + k0 + q * 16;
            bf16* dst = &Bs[row * LDSS + q * 16];
            *(bf16x8*)(dst)     = *(const bf16x8*)(src);
            *(bf16x8*)(dst + 8) = *(const bf16x8*)(src + 8);
        }
        __syncthreads();
#pragma unroll
        for (int ks = 0; ks < 2; ks++) {
            bf16x8 af[4], bfr[2];
#pragma unroll
            for (int mt = 0; mt < 4; mt++)
                af[mt] = *(const bf16x8*)&As[(wm + mt * 16 + lr) * LDSS + ks * 32 + lq * 8];
#pragma unroll
            for (int nt = 0; nt < 2; nt++)
                bfr[nt] = *(const bf16x8*)&Bs[(wn + nt * 16 + lr) * LDSS + ks * 32 + lq * 8];
#pragma unroll
            for (int mt = 0; mt < 4; mt++)
#pragma unroll
                for (int nt = 0; nt < 2; nt++)
                    acc[mt][nt] = MFMA16(af[mt], bfr[nt], acc[mt][nt]);
        }
        __syncthreads();
    }

    // ---- epilogue ----
#pragma unroll
    for (int mt = 0; mt < 4; mt++) {
#pragma unroll
        for (int nt = 0; nt < 2; nt++) {
#pragma unroll
            for (int r = 0; r < 4; r++) {
                int m = m0 + wm + mt * 16 + lq * 4 + r;   // global row (b*2048 + s)
                int n = n0 + wn + nt * 16 + lr;           // global col (h*64 + dk)
                float v = acc[mt][nt][r] + bias[n];
                if constexpr (MODE == 0) {
                    size_t idx = ((size_t)(((m >> 11) * 8 + (n >> 6)) * 2048 + (m & 2047))) * 64 + (n & 63);
                    ((bf16*)Yv)[idx] = (bf16)v;
                } else if constexpr (MODE == 1) {
                    size_t idx = ((size_t)(((m >> 11) * 8 + (n >> 6)) * 64 + (n & 63))) * 2048 + (m & 2047);
                    ((bf16*)Yv)[idx] = (bf16)v;
                } else {
                    ((float*)Yv)[(size_t)m * Dm + n] = v;
                }
            }
        }
    }
}

// ---------------------------------------------------------------------------
// Kernel 3: flash attention. grid = (SX/64, B*H), 256 threads = 4 waves.
// Wave w owns 16 q-rows [blk*64 + w*16, +16).  Iterates SC in 64-key tiles.
// Q,K bf16 [bh][s][dk]; V bf16 transposed [bh][dk][s]; out fp32 [b][s][h*64+dk].
// ---------------------------------------------------------------------------
__global__ __launch_bounds__(256) void attn_kernel(
    const bf16* __restrict__ Qm, const bf16* __restrict__ Km,
    const bf16* __restrict__ Vt, const float* __restrict__ rel,
    float* __restrict__ Oa)
{
    const int bh = blockIdx.y;
    const int h = bh & 7, b = bh >> 3;
    const int t = threadIdx.x;
    const int wid = t >> 6, lane = t & 63, lr = lane & 15, lq = lane >> 4;
    const int q0 = blockIdx.x * 64 + wid * 16;

    __shared__ alignas(16) bf16 Plds[4][16 * LDSS];  // per-wave P tile (16x64, padded)
    __shared__ float Blds[4][80];                    // per-wave rel-bias slice

    const bf16* Qb = Qm + (size_t)bh * SC * DK;
    const bf16* Kb = Km + (size_t)bh * SC * DK;
    const bf16* Vb = Vt + (size_t)bh * DK * SC;

    // Q A-fragments, kept in registers for the whole kernel
    bf16x8 aq0 = *(const bf16x8*)&Qb[(q0 + lr) * DK + lq * 8];
    bf16x8 aq1 = *(const bf16x8*)&Qb[(q0 + lr) * DK + 32 + lq * 8];

    float m_i[4], l_i[4];
    f32x4 oacc[4];
#pragma unroll
    for (int r = 0; r < 4; r++) { m_i[r] = -3.0e38f; l_i[r] = 0.f; }
#pragma unroll
    for (int nt = 0; nt < 4; nt++) oacc[nt] = f32x4{0.f, 0.f, 0.f, 0.f};

    const float sc  = 0.125f * 1.4426950408889634f;  // 1/sqrt(64) * log2(e)
    const float l2e = 1.4426950408889634f;

    for (int k0 = 0; k0 < SC; k0 += 64) {
        // stage bias slice: Blds[wid][i] = rel[(q0-k0-63+i + 2047)*8 + h], i in [0,79)
        int base = (q0 - k0 - 63 + 2047) * 8 + h;
        Blds[wid][lane] = rel[base + lane * 8];
        if (lane < 15) Blds[wid][64 + lane] = rel[base + (64 + lane) * 8];

        // S = Q K^T for 16 q-rows x 64 keys
        f32x4 s[4];
#pragma unroll
        for (int nt = 0; nt < 4; nt++) {
            const bf16* kp = &Kb[(k0 + nt * 16 + lr) * DK + lq * 8];
            bf16x8 kb0 = *(const bf16x8*)kp;
            bf16x8 kb1 = *(const bf16x8*)(kp + 32);
            f32x4 a = f32x4{0.f, 0.f, 0.f, 0.f};
            a = MFMA16(aq0, kb0, a);
            a = MFMA16(aq1, kb1, a);
            s[nt] = a;
        }
        // scale + bias (exp2 domain), tile row-max
        float tmax[4] = {-3.0e38f, -3.0e38f, -3.0e38f, -3.0e38f};
#pragma unroll
        for (int nt = 0; nt < 4; nt++) {
#pragma unroll
            for (int r = 0; r < 4; r++) {
                int i = (lq * 4 + r) - (nt * 16 + lr) + 63;  // in [0,78]
                float v = s[nt][r] * sc + Blds[wid][i] * l2e;
                s[nt][r] = v;
                tmax[r] = fmaxf(tmax[r], v);
            }
        }
#pragma unroll
        for (int off = 8; off >= 1; off >>= 1)
#pragma unroll
            for (int r = 0; r < 4; r++)
                tmax[r] = fmaxf(tmax[r], __shfl_xor(tmax[r], off, 64));

        float alpha[4], rsum[4];
#pragma unroll
        for (int r = 0; r < 4; r++) {
            float mn = fmaxf(m_i[r], tmax[r]);
            alpha[r] = __builtin_amdgcn_exp2f(m_i[r] - mn);
            m_i[r] = mn;
            rsum[r] = 0.f;
        }
        // P = exp2(S - m), write to LDS (D-layout -> A-layout transpose)
#pragma unroll
        for (int nt = 0; nt < 4; nt++) {
#pragma unroll
            for (int r = 0; r < 4; r++) {
                float p = __builtin_amdgcn_exp2f(s[nt][r] - m_i[r]);
                rsum[r] += p;
                Plds[wid][(lq * 4 + r) * LDSS + nt * 16 + lr] = (bf16)p;
            }
        }
#pragma unroll
        for (int off = 8; off >= 1; off >>= 1)
#pragma unroll
            for (int r = 0; r < 4; r++)
                rsum[r] += __shfl_xor(rsum[r], off, 64);
#pragma unroll
        for (int r = 0; r < 4; r++) l_i[r] = l_i[r] * alpha[r] + rsum[r];
#pragma unroll
        for (int nt = 0; nt < 4; nt++)
#pragma unroll
            for (int r = 0; r < 4; r++) oacc[nt][r] *= alpha[r];

        // P A-fragments from LDS
        bf16x8 pa0 = *(const bf16x8*)&Plds[wid][lr * LDSS + lq * 8];
        bf16x8 pa1 = *(const bf16x8*)&Plds[wid][lr * LDSS + 32 + lq * 8];
        // O += P @ V   (B-operand rows = dk, k = key -> contiguous in Vt)
#pragma unroll
        for (int nt = 0; nt < 4; nt++) {
            const bf16* vp = &Vb[(nt * 16 + lr) * SC + k0 + lq * 8];
            bf16x8 vb0 = *(const bf16x8*)vp;
            bf16x8 vb1 = *(const bf16x8*)(vp + 32);
            oacc[nt] = MFMA16(pa0, vb0, oacc[nt]);
            oacc[nt] = MFMA16(pa1, vb1, oacc[nt]);
        }
    }

    // epilogue: O / l  -> fp32 [b][q][h*64+dk]
    float rcp[4];
#pragma unroll
    for (int r = 0; r < 4; r++) rcp[r] = 1.0f / l_i[r];
#pragma unroll
    for (int nt = 0; nt < 4; nt++) {
#pragma unroll
        for (int r = 0; r < 4; r++) {
            int q = q0 + lq * 4 + r;
            Oa[(size_t)(b * SX + q) * Dm + h * 64 + nt * 16 + lr] = oacc[nt][r] * rcp[r];
        }
    }
}

// ---------------------------------------------------------------------------
// Launch
// ---------------------------------------------------------------------------
extern "C" void kernel_launch(void* const* d_in, const int* in_sizes, int n_in,
                              void* d_out, int out_size, void* d_ws, size_t ws_size,
                              hipStream_t stream)
{
    (void)in_sizes; (void)n_in; (void)out_size; (void)ws_size;

    const float* x   = (const float*)d_in[0];
    const float* c   = (const float*)d_in[1];
    const float* Wq  = (const float*)d_in[2];
    const float* bq  = (const float*)d_in[3];
    const float* Wk  = (const float*)d_in[4];
    const float* bk  = (const float*)d_in[5];
    const float* Wv  = (const float*)d_in[6];
    const float* bv  = (const float*)d_in[7];
    const float* Wo  = (const float*)d_in[8];
    const float* bo  = (const float*)d_in[9];
    const float* rel = (const float*)d_in[10];

    char* ws = (char*)d_ws;
    // layout (bytes):
    //   Wbf:  0        .. 2097152   (4 x 512*512 bf16)
    //   Q:    2097152  .. +8388608  (4*8*2048*64 bf16)
    //   K:    10485760 .. +8388608
    //   Vt:   18874368 .. +8388608
    //   attn: 27262976 .. +16777216 (8192*512 fp32)
    bf16*  Wbf = (bf16*)ws;
    bf16*  Qw  = (bf16*)(ws + 2097152);
    bf16*  Kw  = (bf16*)(ws + 10485760);
    bf16*  Vw  = (bf16*)(ws + 18874368);
    float* Aw  = (float*)(ws + 27262976);

    cvt_weights<<<1024, 256, 0, stream>>>(Wq, Wk, Wv, Wo, Wbf);

    dim3 pg(64, 8);  // M/128, N/64
    proj_gemm<0><<<pg, 256, 0, stream>>>(x, Wbf + 0 * 262144, bq, Qw);
    proj_gemm<0><<<pg, 256, 0, stream>>>(c, Wbf + 1 * 262144, bk, Kw);
    proj_gemm<1><<<pg, 256, 0, stream>>>(c, Wbf + 2 * 262144, bv, Vw);

    attn_kernel<<<dim3(SX / 64, Bsz * H), 256, 0, stream>>>(Qw, Kw, Vw, rel, Aw);

    proj_gemm<2><<<pg, 256, 0, stream>>>(Aw, Wbf + 3 * 262144, bo, d_out);
}

// Round 2
// 336.526 us; speedup vs baseline: 1.2406x; 1.2406x over previous
//
#include <hip/hip_runtime.h>
#include <hip/hip_bf16.h>
#include <cstdint>
#include <cstddef>

typedef __bf16 bf16;
typedef __bf16 bf16x4 __attribute__((ext_vector_type(4)));
typedef __bf16 bf16x8 __attribute__((ext_vector_type(8)));
typedef float f32x4 __attribute__((ext_vector_type(4)));
typedef float f32x16 __attribute__((ext_vector_type(16)));

#define MFMA16(a, b, c) __builtin_amdgcn_mfma_f32_16x16x32_bf16((a), (b), (c), 0, 0, 0)
#define MFMA32(a, b, c) __builtin_amdgcn_mfma_f32_32x32x16_bf16((a), (b), (c), 0, 0, 0)

// Problem constants
constexpr int Bsz = 4, SX = 2048, SC = 2048, Dm = 512, H = 8, DK = 64;

// ---------------------------------------------------------------------------
// Kernel 1: convert the 4 weight matrices (each 512x512 fp32) to bf16,
// packed contiguously: Wq | Wk | Wv | Wo
// ---------------------------------------------------------------------------
__global__ __launch_bounds__(256) void cvt_weights(
    const float* __restrict__ Wq, const float* __restrict__ Wk,
    const float* __restrict__ Wv, const float* __restrict__ Wo,
    bf16* __restrict__ out)
{
    int i = (blockIdx.x * 256 + threadIdx.x) * 4;   // 0 .. 4*262144-1
    int w = i >> 18;                                 // which weight
    int off = i & 262143;
    const float* src = (w == 0) ? Wq : (w == 1) ? Wk : (w == 2) ? Wv : Wo;
    float4 v = *(const float4*)(src + off);
    bf16x4 o = { (bf16)v.x, (bf16)v.y, (bf16)v.z, (bf16)v.w };
    *(bf16x4*)(out + i) = o;
}

// Transpose rel_table (4095 x 8) -> relT (8 x 4095), fp32.
// grid (16, 8), 256 threads.
__global__ __launch_bounds__(256) void cvt_rel(
    const float* __restrict__ rel, float* __restrict__ relT)
{
    int h = blockIdx.y;
    int i = blockIdx.x * 256 + threadIdx.x;
    if (i < SX + SC - 1) relT[h * (SX + SC - 1) + i] = rel[i * H + h];
}

// ---------------------------------------------------------------------------
// Kernel 2: Y = X @ W^T + bias.  X fp32 (M x 512), W bf16 (N-slice x 512).
// Block tile 128(M) x 64(N), BK=64, 256 threads = 4 waves (2x2 of 64x32).
// MODE 0: Y bf16 at [(b*8+h)*2048 + s]*64 + dk      (Q, K layout)
// MODE 1: Y bf16 at [(b*8+h)*64 + dk]*2048 + s      (V transposed)
// MODE 2: Y fp32 at m*512 + n                        (final output)
// ---------------------------------------------------------------------------
constexpr int LDSS = 72;  // padded k-stride (bf16 elems)

template <int MODE>
__global__ __launch_bounds__(256) void proj_gemm(
    const float* __restrict__ X, const bf16* __restrict__ W,
    const float* __restrict__ bias, void* __restrict__ Yv)
{
    __shared__ alignas(16) bf16 As[128 * LDSS];
    __shared__ alignas(16) bf16 Bs[64 * LDSS];

    const int t = threadIdx.x;
    const int m0 = blockIdx.x * 128;
    const int n0 = blockIdx.y * 64;
    const int wid = t >> 6, lane = t & 63, lr = lane & 15, lq = lane >> 4;
    const int wm = (wid >> 1) * 64, wn = (wid & 1) * 32;

    f32x4 acc[4][2];
#pragma unroll
    for (int i = 0; i < 4; i++)
#pragma unroll
        for (int j = 0; j < 2; j++) acc[i][j] = f32x4{0.f, 0.f, 0.f, 0.f};

    for (int k0 = 0; k0 < Dm; k0 += 64) {
        // ---- stage A (fp32 -> bf16): 128 rows x 64 k, 2 threads/row ----
        {
            int row = t >> 1, half = t & 1;
            const float* src = X + (size_t)(m0 + row) * Dm + k0 + half * 32;
            bf16* dst = &As[row * LDSS + half * 32];
#pragma unroll
            for (int i = 0; i < 4; i++) {
                float4 v0 = *(const float4*)(src + i * 8);
                float4 v1 = *(const float4*)(src + i * 8 + 4);
                bf16x8 o = { (bf16)v0.x, (bf16)v0.y, (bf16)v0.z, (bf16)v0.w,
                             (bf16)v1.x, (bf16)v1.y, (bf16)v1.z, (bf16)v1.w };
                *(bf16x8*)(dst + i * 8) = o;
            }
        }
        // ---- stage B (bf16): 64 rows x 64 k, 4 threads/row ----
        {
            int row = t >> 2, q = t & 3;
            const bf16* src = W + (size_t)(n0 + row) * Dm + k0 + q * 16;
            bf16* dst = &Bs[row * LDSS + q * 16];
            *(bf16x8*)(dst)     = *(const bf16x8*)(src);
            *(bf16x8*)(dst + 8) = *(const bf16x8*)(src + 8);
        }
        __syncthreads();
#pragma unroll
        for (int ks = 0; ks < 2; ks++) {
            bf16x8 af[4], bfr[2];
#pragma unroll
            for (int mt = 0; mt < 4; mt++)
                af[mt] = *(const bf16x8*)&As[(wm + mt * 16 + lr) * LDSS + ks * 32 + lq * 8];
#pragma unroll
            for (int nt = 0; nt < 2; nt++)
                bfr[nt] = *(const bf16x8*)&Bs[(wn + nt * 16 + lr) * LDSS + ks * 32 + lq * 8];
#pragma unroll
            for (int mt = 0; mt < 4; mt++)
#pragma unroll
                for (int nt = 0; nt < 2; nt++)
                    acc[mt][nt] = MFMA16(af[mt], bfr[nt], acc[mt][nt]);
        }
        __syncthreads();
    }

    // ---- epilogue ----
#pragma unroll
    for (int mt = 0; mt < 4; mt++) {
#pragma unroll
        for (int nt = 0; nt < 2; nt++) {
#pragma unroll
            for (int r = 0; r < 4; r++) {
                int m = m0 + wm + mt * 16 + lq * 4 + r;   // global row (b*2048 + s)
                int n = n0 + wn + nt * 16 + lr;           // global col (h*64 + dk)
                float v = acc[mt][nt][r] + bias[n];
                if constexpr (MODE == 0) {
                    size_t idx = ((size_t)(((m >> 11) * 8 + (n >> 6)) * 2048 + (m & 2047))) * 64 + (n & 63);
                    ((bf16*)Yv)[idx] = (bf16)v;
                } else if constexpr (MODE == 1) {
                    size_t idx = ((size_t)(((m >> 11) * 8 + (n >> 6)) * 64 + (n & 63))) * 2048 + (m & 2047);
                    ((bf16*)Yv)[idx] = (bf16)v;
                } else {
                    ((float*)Yv)[(size_t)m * Dm + n] = v;
                }
            }
        }
    }
}

// ---------------------------------------------------------------------------
// Kernel 3: flash attention, v2.
// grid = (SX/32, B*H), 64 threads = 1 wave per block. Wave owns 32 q-rows.
// No running max (scores bounded ~|2| by construction), no per-tile shuffles:
// P = exp2(S*scale*log2e + bias*log2e) directly; l accumulated per-lane.
// S^T via 32x32x16 MFMA (A=K, B=Q) so each lane holds one q-column.
// Q,K bf16 [bh][s][dk]; V bf16 transposed [bh][dk][s]; out fp32 [b][s][h*64+dk].
// ---------------------------------------------------------------------------
constexpr int PST = 72;  // P tile row stride (bf16)

__global__ __launch_bounds__(64) void attn_kernel(
    const bf16* __restrict__ Qm, const bf16* __restrict__ Km,
    const bf16* __restrict__ Vt, const float* __restrict__ relT,
    float* __restrict__ Oa)
{
    const int bh = blockIdx.y;
    const int h = bh & 7, b = bh >> 3;
    const int lane = threadIdx.x;
    const int l31 = lane & 31, l5 = lane >> 5;
    const int q0 = blockIdx.x * 32;

    __shared__ alignas(16) bf16 Ps[32 * PST];   // P tile, [q][key] padded
    __shared__ alignas(16) float Bs[96];        // bias slice * log2e
    __shared__ alignas(16) float Ls[32];        // per-q denominators

    const bf16* Qb = Qm + (size_t)bh * SC * DK;
    const bf16* Kb = Km + (size_t)bh * SC * DK;
    const bf16* Vb = Vt + (size_t)bh * DK * SC;
    const float* rT = relT + h * (SX + SC - 1);

    // Q B-fragments (n=q, k=dk), resident for whole kernel
    bf16x8 qf[4];
#pragma unroll
    for (int ks = 0; ks < 4; ks++)
        qf[ks] = *(const bf16x8*)&Qb[(size_t)(q0 + l31) * DK + ks * 16 + l5 * 8];

    f32x16 oacc[2];
#pragma unroll
    for (int ng = 0; ng < 2; ng++)
#pragma unroll
        for (int r = 0; r < 16; r++) oacc[ng][r] = 0.f;
    float lsum = 0.f;

    const float sc = 0.125f * 1.4426950408889634f;  // 1/sqrt(64) * log2(e)
    const float l2e = 1.4426950408889634f;

    for (int k0 = 0; k0 < SC; k0 += 64) {
        // ---- stage bias slice (95 values), pre-multiplied by log2e ----
        int i0 = q0 - k0 + 1984;  // = q0 - k0 - 63 + 2047
        Bs[lane] = rT[i0 + lane] * l2e;
        if (lane < 31) Bs[64 + lane] = rT[i0 + 64 + lane] * l2e;
        __syncthreads();

        // ---- S^T = K·Q^T per 32-key group; exp2; P->LDS; l partials ----
#pragma unroll
        for (int kg = 0; kg < 2; kg++) {
            f32x16 s;
#pragma unroll
            for (int r = 0; r < 16; r++) s[r] = 0.f;
#pragma unroll
            for (int ks = 0; ks < 4; ks++) {
                bf16x8 kf = *(const bf16x8*)&Kb[(size_t)(k0 + kg * 32 + l31) * DK + ks * 16 + l5 * 8];
                s = MFMA32(kf, qf[ks], s);  // D[key][q]
            }
            float p[16];
#pragma unroll
            for (int r = 0; r < 16; r++) {
                int n = (r & 3) + 8 * (r >> 2) + 4 * l5;          // key_local in group
                int ib = 63 + l31 - (kg * 32 + n);                 // bias LDS index
                p[r] = __builtin_amdgcn_exp2f(s[r] * sc + Bs[ib]);
                lsum += p[r];
            }
#pragma unroll
            for (int r4 = 0; r4 < 4; r4++) {
                bf16x4 pk = { (bf16)p[r4 * 4 + 0], (bf16)p[r4 * 4 + 1],
                              (bf16)p[r4 * 4 + 2], (bf16)p[r4 * 4 + 3] };
                *(bf16x4*)&Ps[l31 * PST + kg * 32 + 8 * r4 + 4 * l5] = pk;
            }
        }
        __syncthreads();

        // ---- O += P @ V ----
        bf16x8 pf[4];
#pragma unroll
        for (int ks = 0; ks < 4; ks++)
            pf[ks] = *(const bf16x8*)&Ps[l31 * PST + ks * 16 + l5 * 8];  // A[m=q][k=key]
#pragma unroll
        for (int ng = 0; ng < 2; ng++) {
#pragma unroll
            for (int ks = 0; ks < 4; ks++) {
                bf16x8 vf = *(const bf16x8*)&Vb[(size_t)(ng * 32 + l31) * SC + k0 + ks * 16 + l5 * 8];
                oacc[ng] = MFMA32(pf[ks], vf, oacc[ng]);  // D[q][dk]
            }
        }
        __syncthreads();
    }

    // ---- epilogue: l full sum, normalize, store fp32 [b][q][h*64+dk] ----
    lsum += __shfl_xor(lsum, 32, 64);
    if (lane < 32) Ls[l31] = lsum;
    __syncthreads();

#pragma unroll
    for (int r4 = 0; r4 < 4; r4++) {
        float4 lv = *(const float4*)&Ls[8 * r4 + 4 * l5];
        float rv[4] = { 1.f / lv.x, 1.f / lv.y, 1.f / lv.z, 1.f / lv.w };
#pragma unroll
        for (int ng = 0; ng < 2; ng++) {
#pragma unroll
            for (int r0 = 0; r0 < 4; r0++) {
                int row = r0 + 8 * r4 + 4 * l5;  // q_local
                Oa[((size_t)(b * SX + q0 + row)) * Dm + h * 64 + ng * 32 + l31] =
                    oacc[ng][r4 * 4 + r0] * rv[r0];
            }
        }
    }
}

// ---------------------------------------------------------------------------
// Launch
// ---------------------------------------------------------------------------
extern "C" void kernel_launch(void* const* d_in, const int* in_sizes, int n_in,
                              void* d_out, int out_size, void* d_ws, size_t ws_size,
                              hipStream_t stream)
{
    (void)in_sizes; (void)n_in; (void)out_size; (void)ws_size;

    const float* x   = (const float*)d_in[0];
    const float* c   = (const float*)d_in[1];
    const float* Wq  = (const float*)d_in[2];
    const float* bq  = (const float*)d_in[3];
    const float* Wk  = (const float*)d_in[4];
    const float* bk  = (const float*)d_in[5];
    const float* Wv  = (const float*)d_in[6];
    const float* bv  = (const float*)d_in[7];
    const float* Wo  = (const float*)d_in[8];
    const float* bo  = (const float*)d_in[9];
    const float* rel = (const float*)d_in[10];

    char* ws = (char*)d_ws;
    // layout (bytes):
    //   Wbf:  0        .. 2097152   (4 x 512*512 bf16)
    //         NOTE: after proj Q/K/V consume Wq/Wk/Wv-bf16, the first 512 KiB
    //         is dead and is reused for relT (8 x 4095 fp32 = 131040 B).
    //   Q:    2097152  .. +8388608  (4*8*2048*64 bf16)
    //   K:    10485760 .. +8388608
    //   Vt:   18874368 .. +8388608
    //   attn: 27262976 .. +16777216 (8192*512 fp32)
    bf16*  Wbf  = (bf16*)ws;
    float* relT = (float*)ws;            // overwrites Wq-bf16 region (dead by then)
    bf16*  Qw   = (bf16*)(ws + 2097152);
    bf16*  Kw   = (bf16*)(ws + 10485760);
    bf16*  Vw   = (bf16*)(ws + 18874368);
    float* Aw   = (float*)(ws + 27262976);

    cvt_weights<<<1024, 256, 0, stream>>>(Wq, Wk, Wv, Wo, Wbf);

    dim3 pg(64, 8);  // M/128, N/64
    proj_gemm<0><<<pg, 256, 0, stream>>>(x, Wbf + 0 * 262144, bq, Qw);
    proj_gemm<0><<<pg, 256, 0, stream>>>(c, Wbf + 1 * 262144, bk, Kw);
    proj_gemm<1><<<pg, 256, 0, stream>>>(c, Wbf + 2 * 262144, bv, Vw);

    cvt_rel<<<dim3(16, 8), 256, 0, stream>>>(rel, relT);

    attn_kernel<<<dim3(SX / 32, Bsz * H), 64, 0, stream>>>(Qw, Kw, Vw, relT, Aw);

    proj_gemm<2><<<pg, 256, 0, stream>>>(Aw, Wbf + 3 * 262144, bo, d_out);
}

// Round 3
// 256.913 us; speedup vs baseline: 1.6251x; 1.3099x over previous
//
#include <hip/hip_runtime.h>
#include <hip/hip_bf16.h>
#include <cstdint>
#include <cstddef>

typedef __bf16 bf16;
typedef __bf16 bf16x4 __attribute__((ext_vector_type(4)));
typedef __bf16 bf16x8 __attribute__((ext_vector_type(8)));
typedef float f32x4 __attribute__((ext_vector_type(4)));
typedef float f32x16 __attribute__((ext_vector_type(16)));

#define MFMA16(a, b, c) __builtin_amdgcn_mfma_f32_16x16x32_bf16((a), (b), (c), 0, 0, 0)
#define MFMA32(a, b, c) __builtin_amdgcn_mfma_f32_32x32x16_bf16((a), (b), (c), 0, 0, 0)
// async global->LDS, 16B per lane; LDS dst = wave-uniform base + lane*16
#define GLD16(g, l) __builtin_amdgcn_global_load_lds( \
    (const __attribute__((address_space(1))) void*)(g), \
    (__attribute__((address_space(3))) void*)(l), 16, 0, 0)

constexpr int Bsz = 4, SX = 2048, SC = 2048, Dm = 512, H = 8, DK = 64;
constexpr float L2E = 1.4426950408889634f;

// ---------------------------------------------------------------------------
// Kernel 1: weights fp32 -> bf16, packed Wq|Wk|Wv|Wo
// ---------------------------------------------------------------------------
__global__ __launch_bounds__(256) void cvt_weights(
    const float* __restrict__ Wq, const float* __restrict__ Wk,
    const float* __restrict__ Wv, const float* __restrict__ Wo,
    bf16* __restrict__ out)
{
    int i = (blockIdx.x * 256 + threadIdx.x) * 4;
    int w = i >> 18;
    int off = i & 262143;
    const float* src = (w == 0) ? Wq : (w == 1) ? Wk : (w == 2) ? Wv : Wo;
    float4 v = *(const float4*)(src + off);
    bf16x4 o = { (bf16)v.x, (bf16)v.y, (bf16)v.z, (bf16)v.w };
    *(bf16x4*)(out + i) = o;
}

// Kernel 1b: x | c fp32 -> bf16 packed (4M elems each)
__global__ __launch_bounds__(256) void cvt_xc(
    const float* __restrict__ x, const float* __restrict__ c,
    bf16* __restrict__ out)
{
    int i = (blockIdx.x * 256 + threadIdx.x) * 4;   // 0 .. 8M-1
    const float* src = (i < 4194304) ? x : c;
    int off = i & 4194303;
    float4 v = *(const float4*)(src + off);
    bf16x4 o = { (bf16)v.x, (bf16)v.y, (bf16)v.z, (bf16)v.w };
    *(bf16x4*)(out + i) = o;
}

// Kernel 1c: rel_table (4095 x 8) -> relT (8 x 4095), pre-scaled by log2(e)
__global__ __launch_bounds__(256) void cvt_rel(
    const float* __restrict__ rel, float* __restrict__ relT)
{
    int h = blockIdx.y;
    int i = blockIdx.x * 256 + threadIdx.x;
    if (i < SX + SC - 1) relT[h * (SX + SC - 1) + i] = rel[i * H + h] * L2E;
}

// ---------------------------------------------------------------------------
// Kernel 2: Y = A @ W^T + bias.  A bf16 (M x 512, row-major), W bf16 (N x 512).
// 64x64 tile, BK=64, 256 thr = 4 waves (2x2 of 32x32). global_load_lds staging
// with XOR chunk swizzle (swizzle applied to GLOBAL address; LDS is lane-order).
// MODE 0: Y bf16 [(b*8+h)*2048 + s]*64 + dk   (Q,K)
// MODE 1: Y bf16 [(b*8+h)*64 + dk]*2048 + s   (V^T)
// MODE 2: Y fp32 m*512 + n                    (final out)
// ---------------------------------------------------------------------------
template <int MODE>
__global__ __launch_bounds__(256, 4) void proj_gemm(
    const bf16* __restrict__ A, const bf16* __restrict__ W,
    const float* __restrict__ bias, void* __restrict__ Yv)
{
    __shared__ alignas(16) bf16 As[64 * 64];
    __shared__ alignas(16) bf16 Bs[64 * 64];

    const int t = threadIdx.x;
    const int m0 = blockIdx.x * 64;
    const int n0 = blockIdx.y * 64;
    const int wid = t >> 6, lane = t & 63, lr = lane & 15, lq = lane >> 4;
    const int wm = (wid >> 1) * 32, wn = (wid & 1) * 32;

    const int rl = lane >> 3;                 // row in 8-row staging group
    const int ch = (lane & 7) ^ rl;           // xor-swizzled 16B chunk
    const int xk = (lq ^ (lr & 7)) * 8;       // base k-elem offset for frag reads (ks=0)

    f32x4 acc[2][2];
#pragma unroll
    for (int i = 0; i < 2; i++)
#pragma unroll
        for (int j = 0; j < 2; j++) acc[i][j] = f32x4{0.f, 0.f, 0.f, 0.f};

    for (int k0 = 0; k0 < Dm; k0 += 64) {
        const bf16* ga = A + (size_t)(m0 + wid * 16 + rl) * Dm + k0 + ch * 8;
        const bf16* gb = W + (size_t)(n0 + wid * 16 + rl) * Dm + k0 + ch * 8;
#pragma unroll
        for (int j = 0; j < 2; j++) {
            GLD16(ga + j * 8 * Dm, &As[(wid * 16 + j * 8) * 64]);
            GLD16(gb + j * 8 * Dm, &Bs[(wid * 16 + j * 8) * 64]);
        }
        __syncthreads();
#pragma unroll
        for (int ks = 0; ks < 2; ks++) {
            // logical chunk = ks*4+lq ; phys = logical ^ (row&7)
            bf16x8 af[2], bfr[2];
#pragma unroll
            for (int mt = 0; mt < 2; mt++)
                af[mt] = *(const bf16x8*)&As[(wm + mt * 16 + lr) * 64 + (((ks * 4 + lq) ^ (lr & 7)) * 8)];
#pragma unroll
            for (int nt = 0; nt < 2; nt++)
                bfr[nt] = *(const bf16x8*)&Bs[(wn + nt * 16 + lr) * 64 + (((ks * 4 + lq) ^ (lr & 7)) * 8)];
#pragma unroll
            for (int mt = 0; mt < 2; mt++)
#pragma unroll
                for (int nt = 0; nt < 2; nt++)
                    acc[mt][nt] = MFMA16(af[mt], bfr[nt], acc[mt][nt]);
        }
        __syncthreads();
    }
    (void)xk;

    // epilogue
#pragma unroll
    for (int mt = 0; mt < 2; mt++) {
#pragma unroll
        for (int nt = 0; nt < 2; nt++) {
#pragma unroll
            for (int r = 0; r < 4; r++) {
                int m = m0 + wm + mt * 16 + lq * 4 + r;   // b*2048 + s
                int n = n0 + wn + nt * 16 + lr;           // h*64 + dk
                float v = acc[mt][nt][r] + bias[n];
                if constexpr (MODE == 0) {
                    size_t idx = ((size_t)(((m >> 11) * 8 + (n >> 6)) * 2048 + (m & 2047))) * 64 + (n & 63);
                    ((bf16*)Yv)[idx] = (bf16)v;
                } else if constexpr (MODE == 1) {
                    size_t idx = ((size_t)(((m >> 11) * 8 + (n >> 6)) * 64 + (n & 63))) * 2048 + (m & 2047);
                    ((bf16*)Yv)[idx] = (bf16)v;
                } else {
                    ((float*)Yv)[(size_t)m * Dm + n] = v;
                }
            }
        }
    }
}

// ---------------------------------------------------------------------------
// Kernel 3: flash attention v3.
// 1D grid of 2048 blocks x 128 thr (2 waves). XCD swizzle: id%8 selects XCD;
// bh = xcd + 8*(j&3), q-tile = j>>2  ->  all 64 blocks of a bh share one XCD
// (K/V stays in that XCD's L2). Wave w handles keys [w*1024, w*1024+1024),
// barrier-free K-loop; one barrier for the 2-way partial-sum combine.
// ---------------------------------------------------------------------------
constexpr int PST = 72;  // P row stride (bf16)

__global__ __launch_bounds__(128, 4) void attn_kernel(
    const bf16* __restrict__ Qm, const bf16* __restrict__ Km,
    const bf16* __restrict__ Vt, const float* __restrict__ relT,
    bf16* __restrict__ Oa)
{
    const int id = blockIdx.x;
    const int xcd = id & 7, j = id >> 3;
    const int bh = xcd + 8 * (j & 3);
    const int q0 = (j >> 2) * 32;
    const int h = bh & 7, b = bh >> 3;
    const int t = threadIdx.x;
    const int wid = t >> 6, lane = t & 63;
    const int l31 = lane & 31, l5 = lane >> 5;

    __shared__ alignas(16) char sm[19456];
    bf16*  Ps   = (bf16*)(sm + wid * 4608);      // per-wave 32 x PST
    float* Osum = (float*)(sm + 9216);           // 64 lanes x 36 floats
    float* Bsl  = (float*)(sm + 18432) + wid * 96;
    float* Ls1  = (float*)(sm + 19200);
    float* Lfin = (float*)(sm + 19328);

    const bf16* Qb = Qm + (size_t)bh * SC * DK;
    const bf16* Kb = Km + (size_t)bh * SC * DK;
    const bf16* Vb = Vt + (size_t)bh * DK * SC;
    const float* rT = relT + h * (SX + SC - 1);

    // Q B-fragments (n=q, k=dk), resident all kernel
    bf16x8 qf[4];
#pragma unroll
    for (int ks = 0; ks < 4; ks++)
        qf[ks] = *(const bf16x8*)&Qb[(size_t)(q0 + l31) * DK + ks * 16 + l5 * 8];

    f32x16 oacc[2];
#pragma unroll
    for (int ng = 0; ng < 2; ng++)
#pragma unroll
        for (int r = 0; r < 16; r++) oacc[ng][r] = 0.f;
    float lsum = 0.f;

    const float sc = 0.125f * L2E;
    const int kw0 = wid << 10;

#pragma unroll 1
    for (int t16 = 0; t16 < 16; ++t16) {
        const int k0 = kw0 + t16 * 64;
        // bias slice (95 values), relT pre-scaled by log2e
        int i0 = q0 - k0 + 1984;
        Bsl[lane] = rT[i0 + lane];
        if (lane < 31) Bsl[64 + lane] = rT[i0 + 64 + lane];

#pragma unroll
        for (int kg = 0; kg < 2; kg++) {
            f32x16 s;
#pragma unroll
            for (int r = 0; r < 16; r++) s[r] = 0.f;
#pragma unroll
            for (int ks = 0; ks < 4; ks++) {
                bf16x8 kf = *(const bf16x8*)&Kb[(size_t)(k0 + kg * 32 + l31) * DK + ks * 16 + l5 * 8];
                s = MFMA32(kf, qf[ks], s);  // D[key][q], lane col = q
            }
#pragma unroll
            for (int r4 = 0; r4 < 4; r4++) {
                float p[4];
#pragma unroll
                for (int r0 = 0; r0 < 4; r0++) {
                    int n = r0 + 8 * r4 + 4 * l5;           // key_local
                    int ib = 63 + l31 - (kg * 32 + n);
                    p[r0] = __builtin_amdgcn_exp2f(s[r4 * 4 + r0] * sc + Bsl[ib]);
                    lsum += p[r0];
                }
                bf16x4 pk = { (bf16)p[0], (bf16)p[1], (bf16)p[2], (bf16)p[3] };
                *(bf16x4*)&Ps[l31 * PST + kg * 32 + 8 * r4 + 4 * l5] = pk;
            }
        }
        // O += P @ V  (same-wave LDS RAW -> compiler waitcnt, no barrier)
        bf16x8 pf[4];
#pragma unroll
        for (int ks = 0; ks < 4; ks++)
            pf[ks] = *(const bf16x8*)&Ps[l31 * PST + ks * 16 + l5 * 8];
#pragma unroll
        for (int ng = 0; ng < 2; ng++) {
#pragma unroll
            for (int ks = 0; ks < 4; ks++) {
                bf16x8 vf = *(const bf16x8*)&Vb[(size_t)(ng * 32 + l31) * SC + k0 + ks * 16 + l5 * 8];
                oacc[ng] = MFMA32(pf[ks], vf, oacc[ng]);  // D[q][dk], lane col = dk
            }
        }
    }

    // ---- 2-way combine ----
    lsum += __shfl_xor(lsum, 32, 64);
    if (wid == 1) {
        if (lane < 32) Ls1[l31] = lsum;
        float* Op = Osum + lane * 36;
#pragma unroll
        for (int ng = 0; ng < 2; ng++)
#pragma unroll
            for (int q = 0; q < 4; q++) {
                f32x4 v = { oacc[ng][q * 4 + 0], oacc[ng][q * 4 + 1],
                            oacc[ng][q * 4 + 2], oacc[ng][q * 4 + 3] };
                *(f32x4*)(Op + ng * 16 + q * 4) = v;
            }
    }
    __syncthreads();
    if (wid == 0) {
        lsum += Ls1[l31];
        const float* Op = Osum + lane * 36;
#pragma unroll
        for (int ng = 0; ng < 2; ng++)
#pragma unroll
            for (int q = 0; q < 4; q++) {
                f32x4 v = *(const f32x4*)(Op + ng * 16 + q * 4);
#pragma unroll
                for (int r0 = 0; r0 < 4; r0++) oacc[ng][q * 4 + r0] += v[r0];
            }
        if (lane < 32) Lfin[l31] = lsum;
        // epilogue: normalize, store bf16 [b][q][h*64+dk]
#pragma unroll
        for (int r4 = 0; r4 < 4; r4++) {
            float4 lv = *(const float4*)&Lfin[8 * r4 + 4 * l5];
            float rv[4] = { 1.f / lv.x, 1.f / lv.y, 1.f / lv.z, 1.f / lv.w };
#pragma unroll
            for (int ng = 0; ng < 2; ng++) {
#pragma unroll
                for (int r0 = 0; r0 < 4; r0++) {
                    int row = r0 + 8 * r4 + 4 * l5;
                    Oa[((size_t)(b * SX + q0 + row)) * Dm + h * 64 + ng * 32 + l31] =
                        (bf16)(oacc[ng][r4 * 4 + r0] * rv[r0]);
                }
            }
        }
    }
}

// ---------------------------------------------------------------------------
// Launch
// ---------------------------------------------------------------------------
extern "C" void kernel_launch(void* const* d_in, const int* in_sizes, int n_in,
                              void* d_out, int out_size, void* d_ws, size_t ws_size,
                              hipStream_t stream)
{
    (void)in_sizes; (void)n_in; (void)out_size; (void)ws_size;

    const float* x   = (const float*)d_in[0];
    const float* c   = (const float*)d_in[1];
    const float* Wq  = (const float*)d_in[2];
    const float* bq  = (const float*)d_in[3];
    const float* Wk  = (const float*)d_in[4];
    const float* bk  = (const float*)d_in[5];
    const float* Wv  = (const float*)d_in[6];
    const float* bv  = (const float*)d_in[7];
    const float* Wo  = (const float*)d_in[8];
    const float* bo  = (const float*)d_in[9];
    const float* rel = (const float*)d_in[10];

    char* ws = (char*)d_ws;
    // layout (bytes):
    //   Wbf:   0        .. 2 MB      (4 x 512*512 bf16)
    //   XCbf:  2 MB     .. 18 MB     (x|c bf16; DEAD after V-proj)
    //   Aw:    2 MB     (overlays XCbf; attn bf16 out, 8 MB)
    //   Q:     18 MB .. 26 MB ; K: 26..34 ; Vt: 34..42
    //   relT:  42 MB .. +128 KB
    bf16*  Wbf  = (bf16*)ws;
    bf16*  XCbf = (bf16*)(ws + (2u << 20));
    bf16*  Xbf  = XCbf;
    bf16*  Cbf  = XCbf + 4194304;
    bf16*  Aw   = (bf16*)(ws + (2u << 20));      // overlays XCbf (dead by then)
    bf16*  Qw   = (bf16*)(ws + (18u << 20));
    bf16*  Kw   = (bf16*)(ws + (26u << 20));
    bf16*  Vw   = (bf16*)(ws + (34u << 20));
    float* relT = (float*)(ws + (42u << 20));

    cvt_weights<<<1024, 256, 0, stream>>>(Wq, Wk, Wv, Wo, Wbf);
    cvt_xc<<<8192, 256, 0, stream>>>(x, c, XCbf);
    cvt_rel<<<dim3(16, 8), 256, 0, stream>>>(rel, relT);

    dim3 pg(128, 8);  // M/64, N/64
    proj_gemm<0><<<pg, 256, 0, stream>>>(Xbf, Wbf + 0 * 262144, bq, Qw);
    proj_gemm<0><<<pg, 256, 0, stream>>>(Cbf, Wbf + 1 * 262144, bk, Kw);
    proj_gemm<1><<<pg, 256, 0, stream>>>(Cbf, Wbf + 2 * 262144, bv, Vw);

    attn_kernel<<<2048, 128, 0, stream>>>(Qw, Kw, Vw, relT, Aw);

    proj_gemm<2><<<pg, 256, 0, stream>>>(Aw, Wbf + 3 * 262144, bo, d_out);
}